// Round 1
// baseline (1012.336 us; speedup 1.0000x reference)
//
#include <hip/hip_runtime.h>
#include <math.h>

// GCN on 50000 disjoint 21-node hand-skeleton graphs (fixed topology).
// Fused: aggregate-before-matmul, BN folded into W/b, pooling commuted past W3.

#define G_TOTAL 50000
#define NPG 21
#define GPB 6                                  // graphs per chunk
#define NCHUNK ((G_TOTAL + GPB - 1) / GPB)     // 8334
#define H1F 64
#define H2F 128
#define NCLS 29
#define BN_EPS 1e-5f
#define INV_SQRT2 0.70710678118654752440f
#define ROOT_COLSUM 4.53553390593273762f       // 1 + 5/sqrt(2)

// ws float layout: [0..191] W1f, [192..255] b1f, [256..8447] W2f, [8448..8575] b2f
#define WS_W1 0
#define WS_B1 192
#define WS_W2 256
#define WS_B2 8448
#define WS_TOTAL 8576

__global__ void prep_kernel(const float* __restrict__ W1, const float* __restrict__ b1,
                            const float* __restrict__ g1, const float* __restrict__ be1,
                            const float* __restrict__ m1, const float* __restrict__ v1,
                            const float* __restrict__ W2, const float* __restrict__ b2,
                            const float* __restrict__ g2, const float* __restrict__ be2,
                            const float* __restrict__ m2, const float* __restrict__ v2,
                            float* __restrict__ ws) {
    int t = blockIdx.x * blockDim.x + threadIdx.x;
    if (t < 192) {                              // W1f[i][j] = W1[i*64+j]*s1[j]
        int j = t & 63;
        float s = g1[j] * rsqrtf(v1[j] + BN_EPS);
        ws[WS_W1 + t] = W1[t] * s;
    } else if (t < 256) {                       // b1f
        int j = t - 192;
        float s = g1[j] * rsqrtf(v1[j] + BN_EPS);
        ws[WS_B1 + j] = (b1[j] - m1[j]) * s + be1[j];
    } else if (t < 256 + 8192) {                // W2f[k][j] = W2[k*128+j]*s2[j]
        int i = t - 256;
        int j = i & 127;
        float s = g2[j] * rsqrtf(v2[j] + BN_EPS);
        ws[WS_W2 + i] = W2[i] * s;
    } else if (t < 256 + 8192 + 128) {          // b2f
        int j = t - (256 + 8192);
        float s = g2[j] * rsqrtf(v2[j] + BN_EPS);
        ws[WS_B2 + j] = (b2[j] - m2[j]) * s + be2[j];
    }
}

__global__ __launch_bounds__(256, 2)
void gcn_main(const float* __restrict__ x, const float* __restrict__ W3,
              const float* __restrict__ b3, const float* __restrict__ ws,
              float* __restrict__ out) {
    __shared__ float sW2[H1F * H2F];    // [k*128 + j], 32 KB
    __shared__ float sZ[H1F][136];      // z1 transposed [k][row], 128 rows + 8 pad, 34.8 KB
    __shared__ float sW1[3 * 64];
    __shared__ float sb1[64];
    __shared__ float sb2[128];
    __shared__ float sb3[32];
    __shared__ float sP[GPB * H2F];     // pooled pre-W3 accumulator [g][128]
    __shared__ float sLg[GPB * NCLS];   // logits
    __shared__ float sRed[GPB * 2];     // max, log-sum-exp per graph

    const int tid = threadIdx.x;

    // --- load folded weights once per block ---
    sW1[tid & 255] = (tid < 192) ? ws[WS_W1 + tid] : 0.f;   // only first 192 used
    if (tid < 192) sW1[tid] = ws[WS_W1 + tid];
    if (tid < 64)  sb1[tid] = ws[WS_B1 + tid];
    for (int i = tid; i < 8192; i += 256) sW2[i] = ws[WS_W2 + i];
    if (tid < 128) sb2[tid] = ws[WS_B2 + tid];
    if (tid < NCLS) sb3[tid] = b3[tid];
    __syncthreads();

    for (int chunk = blockIdx.x; chunk < NCHUNK; chunk += gridDim.x) {
        const int g0 = chunk * GPB;
        const int nv = min(GPB, G_TOTAL - g0);
        const int Mrows = nv * NPG;

        // zero pooled accumulator (6*128 = 768)
        sP[tid] = 0.f; sP[tid + 256] = 0.f; sP[tid + 512] = 0.f;

        // ---- phase 1: z1T[k][row] = relu( (A x)[row] . W1f + b1f ) ----
        {
            const int node = tid >> 1;      // 0..127
            const int half = tid & 1;
            float ax0 = 0.f, ax1 = 0.f, ax2 = 0.f;
            if (node < Mrows) {
                const int lg = node / NPG;
                const int j = node - lg * NPG;
                const long long gid = (long long)(g0 + lg) * NPG + j;
                const float* xp = x + gid * 3;
                const float s0 = xp[0], s1 = xp[1], s2 = xp[2];
                if (j == 0) {
                    ax0 = s0; ax1 = s1; ax2 = s2;
                } else {
                    const int pj = ((j & 3) == 1) ? 0 : (j - 1);
                    const float* xq = x + (gid - (j - pj)) * 3;
                    const float c = ((j & 3) == 1) ? INV_SQRT2 : 0.5f;
                    ax0 = fmaf(c, xq[0], 0.5f * s0);
                    ax1 = fmaf(c, xq[1], 0.5f * s1);
                    ax2 = fmaf(c, xq[2], 0.5f * s2);
                }
            }
            const int k0 = half * 32;
            #pragma unroll
            for (int kk = 0; kk < 32; ++kk) {
                const int k = k0 + kk;
                float t = sb1[k];
                t = fmaf(ax0, sW1[k], t);
                t = fmaf(ax1, sW1[64 + k], t);
                t = fmaf(ax2, sW1[128 + k], t);
                t = fmaxf(t, 0.f);
                if (node >= Mrows) t = 0.f;     // zero pad rows so GEMM is clean
                sZ[k][node] = t;
            }
        }
        __syncthreads();

        // ---- phase 1.5: in-place aggregate az1 = A z1 (column-wise over rows) ----
        {
            const int row = tid >> 1;
            const int half = tid & 1;
            const int k0 = half * 32;
            const int lg = row / NPG;
            const int j = row - lg * NPG;
            const bool doit = (row < Mrows) && (j != 0);   // j==0: az = z
            const int pj = ((j & 3) == 1) ? 0 : (j - 1);
            const int prow = row - (j - pj);
            const float c = ((j & 3) == 1) ? INV_SQRT2 : 0.5f;
            float vreg[32];
            if (doit) {
                #pragma unroll
                for (int kk = 0; kk < 32; ++kk)
                    vreg[kk] = fmaf(c, sZ[k0 + kk][prow], 0.5f * sZ[k0 + kk][row]);
            }
            __syncthreads();
            if (doit) {
                #pragma unroll
                for (int kk = 0; kk < 32; ++kk) sZ[k0 + kk][row] = vreg[kk];
            }
        }
        __syncthreads();

        // ---- phase 2: GEMM [128 x 64] x [64 x 128], 8x8 per thread; fused
        //      bias + relu + weighted pool into sP ----
        {
            const int ty = tid >> 4, tx = tid & 15;
            const int r0 = ty * 8, c0 = tx * 8;
            float acc[8][8];
            #pragma unroll
            for (int i = 0; i < 8; ++i)
                #pragma unroll
                for (int j2 = 0; j2 < 8; ++j2) acc[i][j2] = 0.f;

            #pragma unroll 2
            for (int k = 0; k < 64; ++k) {
                const float4 a0 = *(const float4*)&sZ[k][r0];
                const float4 a1 = *(const float4*)&sZ[k][r0 + 4];
                const float4 b0 = *(const float4*)&sW2[k * 128 + c0];
                const float4 b1 = *(const float4*)&sW2[k * 128 + c0 + 4];
                const float a[8] = {a0.x, a0.y, a0.z, a0.w, a1.x, a1.y, a1.z, a1.w};
                const float b[8] = {b0.x, b0.y, b0.z, b0.w, b1.x, b1.y, b1.z, b1.w};
                #pragma unroll
                for (int i = 0; i < 8; ++i)
                    #pragma unroll
                    for (int j2 = 0; j2 < 8; ++j2)
                        acc[i][j2] = fmaf(a[i], b[j2], acc[i][j2]);
            }

            #pragma unroll
            for (int i = 0; i < 8; ++i) {
                const int row = r0 + i;
                if (row >= Mrows) continue;
                const int lg = row / NPG;
                const int j = row - lg * NPG;
                const float pwv = ((j == 0) ? ROOT_COLSUM : (((j & 3) == 0) ? 0.5f : 1.0f))
                                  * (1.0f / 21.0f);
                #pragma unroll
                for (int jj = 0; jj < 8; ++jj) {
                    const float z2 = fmaxf(acc[i][jj] + sb2[c0 + jj], 0.f);
                    atomicAdd(&sP[lg * H2F + c0 + jj], z2 * pwv);
                }
            }
        }
        __syncthreads();

        // ---- phase 3: logits = sP . W3 + b3 ; log_softmax ----
        {
            const int nvc = nv * NCLS;
            if (tid < nvc) {
                const int g = tid / NCLS, c = tid - g * NCLS;
                float acc = sb3[c];
                const float* w3c = W3 + c;
                const float* pg = &sP[g * H2F];
                #pragma unroll 4
                for (int k = 0; k < 128; ++k) acc = fmaf(pg[k], w3c[k * NCLS], acc);
                sLg[g * NCLS + c] = acc;
            }
            __syncthreads();
            if (tid < nv) {
                float m = -1e30f;
                for (int c = 0; c < NCLS; ++c) m = fmaxf(m, sLg[tid * NCLS + c]);
                float s = 0.f;
                for (int c = 0; c < NCLS; ++c) s += expf(sLg[tid * NCLS + c] - m);
                sRed[tid * 2] = m;
                sRed[tid * 2 + 1] = logf(s);
            }
            __syncthreads();
            if (tid < nvc) {
                const int g = tid / NCLS, c = tid - g * NCLS;
                out[(long long)(g0 + g) * NCLS + c] =
                    sLg[g * NCLS + c] - sRed[g * 2] - sRed[g * 2 + 1];
            }
        }
        __syncthreads();   // protect sZ/sP/sLg before next chunk
    }
}

extern "C" void kernel_launch(void* const* d_in, const int* in_sizes, int n_in,
                              void* d_out, int out_size, void* d_ws, size_t ws_size,
                              hipStream_t stream) {
    const float* x   = (const float*)d_in[0];
    const float* W1  = (const float*)d_in[1];
    const float* b1  = (const float*)d_in[2];
    const float* g1  = (const float*)d_in[3];
    const float* be1 = (const float*)d_in[4];
    const float* m1  = (const float*)d_in[5];
    const float* v1  = (const float*)d_in[6];
    const float* W2  = (const float*)d_in[7];
    const float* b2  = (const float*)d_in[8];
    const float* g2  = (const float*)d_in[9];
    const float* be2 = (const float*)d_in[10];
    const float* m2  = (const float*)d_in[11];
    const float* v2  = (const float*)d_in[12];
    const float* W3  = (const float*)d_in[13];
    const float* b3  = (const float*)d_in[14];
    float* out = (float*)d_out;
    float* ws  = (float*)d_ws;

    prep_kernel<<<(WS_TOTAL + 255) / 256, 256, 0, stream>>>(
        W1, b1, g1, be1, m1, v1, W2, b2, g2, be2, m2, v2, ws);

    gcn_main<<<2048, 256, 0, stream>>>(x, W3, b3, ws, out);
}

// Round 2
// 393.548 us; speedup vs baseline: 2.5723x; 2.5723x over previous
//
#include <hip/hip_runtime.h>
#include <math.h>

// GCN on 50000 disjoint 21-node hand-skeleton graphs (fixed topology).
// Fused: aggregate-before-matmul, BN folded into W/b, pooling commuted past W3.
// R2: one chunk per block (no tail imbalance), no LDS atomics (register
// partials + tree reduce), W3^T staged in ws, weight-load race fixed.

#define G_TOTAL 50000
#define NPG 21
#define GPB 6                                  // graphs per block
#define NCHUNK ((G_TOTAL + GPB - 1) / GPB)     // 8334
#define H1F 64
#define H2F 128
#define NCLS 29
#define BN_EPS 1e-5f
#define INV_SQRT2 0.70710678118654752440f
#define ROOT_COLSUM 4.53553390593273762f       // 1 + 5/sqrt(2)

// ws float layout
#define WS_W1 0          // 192   W1*bn1 folded
#define WS_B1 192        // 64
#define WS_W2 256        // 8192  W2*bn2 folded
#define WS_B2 8448       // 128
#define WS_B3 8576       // 32    (29 used)
#define WS_W3T 8608      // 29*128 = 3712, [c][k]
#define WS_TOTAL (8608 + 3712)

__global__ void prep_kernel(const float* __restrict__ W1, const float* __restrict__ b1,
                            const float* __restrict__ g1, const float* __restrict__ be1,
                            const float* __restrict__ m1, const float* __restrict__ v1,
                            const float* __restrict__ W2, const float* __restrict__ b2,
                            const float* __restrict__ g2, const float* __restrict__ be2,
                            const float* __restrict__ m2, const float* __restrict__ v2,
                            const float* __restrict__ W3, const float* __restrict__ b3,
                            float* __restrict__ ws) {
    int t = blockIdx.x * blockDim.x + threadIdx.x;
    if (t < 192) {                              // W1f[i][j] = W1[i*64+j]*s1[j]
        int j = t & 63;
        float s = g1[j] * rsqrtf(v1[j] + BN_EPS);
        ws[WS_W1 + t] = W1[t] * s;
    } else if (t < 256) {                       // b1f
        int j = t - 192;
        float s = g1[j] * rsqrtf(v1[j] + BN_EPS);
        ws[WS_B1 + j] = (b1[j] - m1[j]) * s + be1[j];
    } else if (t < 256 + 8192) {                // W2f[k][j] = W2[k*128+j]*s2[j]
        int i = t - 256;
        int j = i & 127;
        float s = g2[j] * rsqrtf(v2[j] + BN_EPS);
        ws[WS_W2 + i] = W2[i] * s;
    } else if (t < WS_B3) {                     // b2f
        int j = t - 8448;
        float s = g2[j] * rsqrtf(v2[j] + BN_EPS);
        ws[WS_B2 + j] = (b2[j] - m2[j]) * s + be2[j];
    } else if (t < WS_W3T) {                    // b3 copy (pad to 32)
        int j = t - WS_B3;
        ws[WS_B3 + j] = (j < NCLS) ? b3[j] : 0.f;
    } else if (t < WS_TOTAL) {                  // W3T[c][k] = W3[k*29+c]
        int i = t - WS_W3T;
        int c = i >> 7, k = i & 127;
        ws[WS_W3T + i] = W3[k * NCLS + c];
    }
}

__global__ __launch_bounds__(256, 2)
void gcn_main(const float* __restrict__ x, const float* __restrict__ ws,
              float* __restrict__ out) {
    __shared__ float sW2[H1F * H2F];    // [k*128+j], 32 KB
    __shared__ float sZ[H1F][132];      // z1^T [k][row], 33.8 KB; reused as partial scratch
    __shared__ float sW1[192];
    __shared__ float sb1[64];
    __shared__ float sb2[128];
    __shared__ float sb3[32];
    __shared__ float sP[GPB * H2F];     // pooled pre-W3 [g][128]
    __shared__ float sLg[GPB * NCLS];
    __shared__ float sRed[GPB * 2];

    const int tid = threadIdx.x;
    const int g0 = blockIdx.x * GPB;
    const int nv = min(GPB, G_TOTAL - g0);
    const int Mrows = nv * NPG;

    // ---- weights (no races: disjoint ranges) ----
    for (int i = tid; i < 8192; i += 256) sW2[i] = ws[WS_W2 + i];
    if (tid < 192) sW1[tid] = ws[WS_W1 + tid];
    else if (tid < 256) sb1[tid - 192] = ws[WS_B1 + (tid - 192)];
    if (tid < 128) sb2[tid] = ws[WS_B2 + tid];
    else if (tid < 160) sb3[tid - 128] = ws[WS_B3 + (tid - 128)];
    __syncthreads();

    // ---- phase 1: z1^T[k][row] = relu((A x)[row] . W1f + b1f), keep own slice in regs ----
    const int node = tid >> 1;          // 0..127
    const int k0 = (tid & 1) * 32;
    float zown[32];
    {
        float ax0 = 0.f, ax1 = 0.f, ax2 = 0.f;
        if (node < Mrows) {
            const int lg = node / NPG;
            const int j = node - lg * NPG;
            const long long gid = (long long)(g0 + lg) * NPG + j;
            const float* xp = x + gid * 3;
            const float s0 = xp[0], s1 = xp[1], s2 = xp[2];
            if (j == 0) { ax0 = s0; ax1 = s1; ax2 = s2; }
            else {
                const int pj = ((j & 3) == 1) ? 0 : (j - 1);
                const float* xq = x + (gid - (j - pj)) * 3;
                const float c = ((j & 3) == 1) ? INV_SQRT2 : 0.5f;
                ax0 = fmaf(c, xq[0], 0.5f * s0);
                ax1 = fmaf(c, xq[1], 0.5f * s1);
                ax2 = fmaf(c, xq[2], 0.5f * s2);
            }
        }
        #pragma unroll
        for (int kk = 0; kk < 32; ++kk) {
            const int k = k0 + kk;
            float t = fmaf(ax0, sW1[k], sb1[k]);
            t = fmaf(ax1, sW1[64 + k], t);
            t = fmaf(ax2, sW1[128 + k], t);
            t = fmaxf(t, 0.f);
            if (node >= Mrows) t = 0.f;
            zown[kk] = t;
            sZ[k][node] = t;
        }
    }
    __syncthreads();

    // ---- phase 1.5: az1 = A z1 (read parents, sync, write back) ----
    {
        const int lg = node / NPG;
        const int j = node - lg * NPG;
        const bool doit = (node < Mrows) && (j != 0);    // j==0: az == z
        const int pj = ((j & 3) == 1) ? 0 : (j - 1);
        const int prow = node - (j - pj);
        const float c = ((j & 3) == 1) ? INV_SQRT2 : 0.5f;
        float az[32];
        if (doit) {
            #pragma unroll
            for (int kk = 0; kk < 32; ++kk)
                az[kk] = fmaf(c, sZ[k0 + kk][prow], 0.5f * zown[kk]);
        }
        __syncthreads();
        if (doit) {
            #pragma unroll
            for (int kk = 0; kk < 32; ++kk) sZ[k0 + kk][node] = az[kk];
        }
    }
    __syncthreads();

    // ---- phase 2: GEMM [128x64]x[64x128], 8x8/thread; bias+relu+weighted
    //      per-graph partials in registers (no atomics) ----
    const int ty = tid >> 4, tx = tid & 15;
    const int r0 = ty * 8, c0 = tx * 8;
    float pA[8], pB[8];
    {
        float acc[8][8];
        #pragma unroll
        for (int i = 0; i < 8; ++i)
            #pragma unroll
            for (int j2 = 0; j2 < 8; ++j2) acc[i][j2] = 0.f;

        #pragma unroll 2
        for (int k = 0; k < 64; ++k) {
            const float4 a0 = *(const float4*)&sZ[k][r0];
            const float4 a1 = *(const float4*)&sZ[k][r0 + 4];
            const float4 b0 = *(const float4*)&sW2[k * 128 + c0];
            const float4 b1 = *(const float4*)&sW2[k * 128 + c0 + 4];
            const float a[8] = {a0.x, a0.y, a0.z, a0.w, a1.x, a1.y, a1.z, a1.w};
            const float b[8] = {b0.x, b0.y, b0.z, b0.w, b1.x, b1.y, b1.z, b1.w};
            #pragma unroll
            for (int i = 0; i < 8; ++i)
                #pragma unroll
                for (int j2 = 0; j2 < 8; ++j2)
                    acc[i][j2] = fmaf(a[i], b[j2], acc[i][j2]);
        }

        #pragma unroll
        for (int jj = 0; jj < 8; ++jj) { pA[jj] = 0.f; pB[jj] = 0.f; }
        const int lgA = r0 / NPG;
        #pragma unroll
        for (int i = 0; i < 8; ++i) {
            const int row = r0 + i;
            if (row < Mrows) {
                const int lg = row / NPG;
                const int j = row - lg * NPG;
                const float w = ((j == 0) ? ROOT_COLSUM : (((j & 3) == 0) ? 0.5f : 1.0f))
                                * (1.0f / 21.0f);
                const bool isA = (lg == lgA);
                #pragma unroll
                for (int jj = 0; jj < 8; ++jj) {
                    const float z2 = fmaxf(acc[i][jj] + sb2[c0 + jj], 0.f);
                    if (isA) pA[jj] = fmaf(w, z2, pA[jj]);
                    else     pB[jj] = fmaf(w, z2, pB[jj]);
                }
            }
        }
    }
    __syncthreads();                    // everyone done reading sZ

    // ---- partial write + reduce (sPart aliases sZ: [16][2][128] = 4096 floats) ----
    float* sPart = &sZ[0][0];
    *(float4*)&sPart[ty * 256 + c0]           = make_float4(pA[0], pA[1], pA[2], pA[3]);
    *(float4*)&sPart[ty * 256 + c0 + 4]       = make_float4(pA[4], pA[5], pA[6], pA[7]);
    *(float4*)&sPart[ty * 256 + 128 + c0]     = make_float4(pB[0], pB[1], pB[2], pB[3]);
    *(float4*)&sPart[ty * 256 + 128 + c0 + 4] = make_float4(pB[4], pB[5], pB[6], pB[7]);
    __syncthreads();

    #pragma unroll
    for (int p = tid; p < GPB * H2F; p += 256) {      // 3 iters: 768 (g,c) sums
        const int lg = p >> 7, c = p & 127;
        if (lg < nv) {
            const int tyS = (NPG * lg) >> 3;
            const int tyE = (NPG * lg + NPG - 1) >> 3;
            float s = 0.f;
            for (int t2 = tyS; t2 <= tyE; ++t2) {
                const int lgA2 = (t2 * 8) / NPG;
                s += (lgA2 == lg) ? sPart[t2 * 256 + c] : sPart[t2 * 256 + 128 + c];
            }
            sP[p] = s;
        }
    }
    __syncthreads();

    // ---- phase 3: logits = sP . W3 + b3 (W3T staged in ws, float4) ----
    if (tid < nv * NCLS) {
        const int g = tid / NCLS, c = tid - g * NCLS;
        const float* w3 = ws + WS_W3T + c * 128;
        const float* pg = &sP[g * H2F];
        float acc3 = sb3[c];
        #pragma unroll
        for (int k = 0; k < 128; k += 4) {
            const float4 wv = *(const float4*)&w3[k];
            const float4 pv = *(const float4*)&pg[k];
            acc3 = fmaf(pv.x, wv.x, acc3);
            acc3 = fmaf(pv.y, wv.y, acc3);
            acc3 = fmaf(pv.z, wv.z, acc3);
            acc3 = fmaf(pv.w, wv.w, acc3);
        }
        sLg[g * NCLS + c] = acc3;
    }
    __syncthreads();
    if (tid < nv) {
        float m = -1e30f;
        for (int c = 0; c < NCLS; ++c) m = fmaxf(m, sLg[tid * NCLS + c]);
        float s = 0.f;
        for (int c = 0; c < NCLS; ++c) s += expf(sLg[tid * NCLS + c] - m);
        sRed[tid * 2] = m;
        sRed[tid * 2 + 1] = logf(s);
    }
    __syncthreads();
    if (tid < nv * NCLS) {
        const int g = tid / NCLS, c = tid - g * NCLS;
        out[(long long)(g0 + g) * NCLS + c] =
            sLg[g * NCLS + c] - sRed[g * 2] - sRed[g * 2 + 1];
    }
}

extern "C" void kernel_launch(void* const* d_in, const int* in_sizes, int n_in,
                              void* d_out, int out_size, void* d_ws, size_t ws_size,
                              hipStream_t stream) {
    const float* x   = (const float*)d_in[0];
    const float* W1  = (const float*)d_in[1];
    const float* b1  = (const float*)d_in[2];
    const float* g1  = (const float*)d_in[3];
    const float* be1 = (const float*)d_in[4];
    const float* m1  = (const float*)d_in[5];
    const float* v1  = (const float*)d_in[6];
    const float* W2  = (const float*)d_in[7];
    const float* b2  = (const float*)d_in[8];
    const float* g2  = (const float*)d_in[9];
    const float* be2 = (const float*)d_in[10];
    const float* m2  = (const float*)d_in[11];
    const float* v2  = (const float*)d_in[12];
    const float* W3  = (const float*)d_in[13];
    const float* b3  = (const float*)d_in[14];
    float* out = (float*)d_out;
    float* ws  = (float*)d_ws;

    prep_kernel<<<(WS_TOTAL + 255) / 256, 256, 0, stream>>>(
        W1, b1, g1, be1, m1, v1, W2, b2, g2, be2, m2, v2, W3, b3, ws);

    gcn_main<<<NCHUNK, 256, 0, stream>>>(x, ws, out);
}

// Round 3
// 216.272 us; speedup vs baseline: 4.6809x; 1.8197x over previous
//
#include <hip/hip_runtime.h>
#include <math.h>

// GCN on 50000 disjoint 21-node hand-skeleton graphs (fixed topology).
// Fused: aggregate-before-matmul, BN folded into W/b, pooling commuted past W3.
// R3: layer-2 GEMM on MFMA (split-bf16 3-pass), fragment-layout LDS (conflict-
// free), B-frags prepacked in ws (L2->regs), pooling via shfl reduce, 4 blk/CU.

#define G_TOTAL 50000
#define NPG 21
#define GPB 6
#define NCHUNK ((G_TOTAL + GPB - 1) / GPB)     // 8334
#define NCLS 29
#define BN_EPS 1e-5f
#define INV_SQRT2 0.70710678118654752440f
#define ROOT_COLSUM 4.53553390593273762f       // 1 + 5/sqrt(2)

// ws layout (float/dword index)
#define WS_W1   0              // 192:  W1*bn1 folded  [3][64]
#define WS_B1   192            // 64
#define WS_B2   256            // 128
#define WS_B3   384            // 32 (29 used)
#define WS_W3T  416            // 3712: W3T [29][128]
#define WS_BF   4160           // 16384 dwords: W2 b-frags hi/lo, bf16-packed
#define WS_TOTAL (WS_BF + 16384)

typedef short s16x8 __attribute__((ext_vector_type(8)));
typedef float f32x4 __attribute__((ext_vector_type(4)));

__device__ __forceinline__ unsigned f2bf(float f) {            // RNE float->bf16
    unsigned u = __float_as_uint(f);
    return (u + 0x7FFFu + ((u >> 16) & 1u)) >> 16;
}
__device__ __forceinline__ float bf2f(unsigned h) { return __uint_as_float(h << 16); }

__device__ __forceinline__ void split2(float v0, float v1, unsigned& hw, unsigned& lw) {
    unsigned h0 = f2bf(v0), h1 = f2bf(v1);
    unsigned l0 = f2bf(v0 - bf2f(h0)), l1 = f2bf(v1 - bf2f(h1));
    hw = (h1 << 16) | h0;
    lw = (l1 << 16) | l0;
}

__global__ void prep_kernel(const float* __restrict__ W1, const float* __restrict__ b1,
                            const float* __restrict__ g1, const float* __restrict__ be1,
                            const float* __restrict__ m1, const float* __restrict__ v1,
                            const float* __restrict__ W2, const float* __restrict__ b2,
                            const float* __restrict__ g2, const float* __restrict__ be2,
                            const float* __restrict__ m2, const float* __restrict__ v2,
                            const float* __restrict__ W3, const float* __restrict__ b3,
                            float* __restrict__ ws) {
    int t = blockIdx.x * blockDim.x + threadIdx.x;
    if (t < 192) {                              // W1f[i][j] = W1[i*64+j]*s1[j]
        int j = t & 63;
        float s = g1[j] * rsqrtf(v1[j] + BN_EPS);
        ws[WS_W1 + t] = W1[t] * s;
    } else if (t < 256) {                       // b1f
        int j = t - 192;
        float s = g1[j] * rsqrtf(v1[j] + BN_EPS);
        ws[WS_B1 + j] = (b1[j] - m1[j]) * s + be1[j];
    } else if (t < 384) {                       // b2f
        int j = t - 256;
        float s = g2[j] * rsqrtf(v2[j] + BN_EPS);
        ws[WS_B2 + j] = (b2[j] - m2[j]) * s + be2[j];
    } else if (t < 416) {                       // b3 (pad 32)
        int j = t - 384;
        ws[WS_B3 + j] = (j < NCLS) ? b3[j] : 0.f;
    } else if (t < WS_BF) {                     // W3T[c][k] = W3[k*29+c]
        int i = t - WS_W3T;
        if (i < 3712) {
            int c = i >> 7, k = i & 127;
            ws[WS_W3T + i] = W3[k * NCLS + c];
        }
    } else if (t < WS_TOTAL) {                  // B-fragments of W2f (bf16 hi/lo)
        int i = t - WS_BF;                      // dword index
        int d = i & 3;                          // dword within 16B frag
        int l = (i >> 2) & 63;                  // lane
        int h = (i >> 8) & 1;                   // 0=hi 1=lo
        int s = (i >> 9) & 1;                   // k-step
        int n = i >> 10;                        // n-tile 0..7
        int g = l >> 4, r = l & 15;
        int c = 16 * n + r;
        float sc = g2[c] * rsqrtf(v2[c] + BN_EPS);
        int k0 = 32 * s + 8 * g + 2 * d;
        float v0 = W2[k0 * 128 + c] * sc;
        float v1v = W2[(k0 + 1) * 128 + c] * sc;
        unsigned hw, lw;
        split2(v0, v1v, hw, lw);
        ((unsigned*)ws)[WS_BF + i] = h ? lw : hw;
    }
}

__global__ __launch_bounds__(256, 4)
void gcn_main(const float* __restrict__ x, const float* __restrict__ ws,
              float* __restrict__ out) {
    // alias buffer: phase1 z1 fp32 [128][68]; phase2 A-frags hi/lo (8192 dw);
    // phase3 W3T [29][132]
    __shared__ float sAlias[8704];
    __shared__ float sP[GPB * 128];
    __shared__ float sW1[192];
    __shared__ float sb1[64];
    __shared__ float sb2[128];
    __shared__ float sb3[32];
    __shared__ float sLg[176];
    __shared__ float sRed[12];

    const int tid = threadIdx.x;
    const int g0 = blockIdx.x * GPB;
    const int nv = min(GPB, G_TOTAL - g0);
    const int Mrows = nv * NPG;

    // ---- stage small weights, zero sP ----
    if (tid < 192) sW1[tid] = ws[WS_W1 + tid];
    else if (tid < 256) sb1[tid - 192] = ws[WS_B1 + (tid - 192)];
    if (tid < 128) sb2[tid] = ws[WS_B2 + tid];
    else if (tid < 160) sb3[tid - 128] = ws[WS_B3 + (tid - 128)];
    #pragma unroll
    for (int p = tid; p < GPB * 128; p += 256) sP[p] = 0.f;
    __syncthreads();

    // ---- phase 1: z1[node][k0..k0+31] = relu((A x)[node].W1f + b1f) ----
    const int node = tid >> 1;          // 0..127
    const int s = tid & 1;              // k-step / half
    const int k0 = s * 32;
    const int lg = node / NPG;
    const int jj21 = node - lg * NPG;
    float zown[32];
    {
        float ax0 = 0.f, ax1 = 0.f, ax2 = 0.f;
        if (node < Mrows) {
            const long long gid = (long long)(g0 + lg) * NPG + jj21;
            const float* xp = x + gid * 3;
            const float s0 = xp[0], s1 = xp[1], s2 = xp[2];
            if (jj21 == 0) { ax0 = s0; ax1 = s1; ax2 = s2; }
            else {
                const int dist = ((jj21 & 3) == 1) ? jj21 : 1;
                const float* xq = x + (gid - dist) * 3;
                const float c = ((jj21 & 3) == 1) ? INV_SQRT2 : 0.5f;
                ax0 = fmaf(c, xq[0], 0.5f * s0);
                ax1 = fmaf(c, xq[1], 0.5f * s1);
                ax2 = fmaf(c, xq[2], 0.5f * s2);
            }
        }
        #pragma unroll
        for (int kk = 0; kk < 32; ++kk) {
            const int k = k0 + kk;
            float t = fmaf(ax0, sW1[k], sb1[k]);
            t = fmaf(ax1, sW1[64 + k], t);
            t = fmaf(ax2, sW1[128 + k], t);
            t = fmaxf(t, 0.f);
            if (node >= Mrows) t = 0.f;
            zown[kk] = t;
        }
        float* z1 = sAlias;
        #pragma unroll
        for (int q = 0; q < 8; ++q)
            *(float4*)&z1[node * 68 + k0 + 4 * q] =
                make_float4(zown[4*q], zown[4*q+1], zown[4*q+2], zown[4*q+3]);
    }
    __syncthreads();

    // ---- phase 1.5a: az = A z1 (read parents) ----
    float az[32];
    {
        const float* z1 = sAlias;
        if (jj21 != 0) {
            const int dist = ((jj21 & 3) == 1) ? jj21 : 1;
            const int prow = node - dist;
            const float c = ((jj21 & 3) == 1) ? INV_SQRT2 : 0.5f;
            #pragma unroll
            for (int q = 0; q < 8; ++q) {
                const float4 zp = *(const float4*)&z1[prow * 68 + k0 + 4 * q];
                az[4*q]   = fmaf(c, zp.x, 0.5f * zown[4*q]);
                az[4*q+1] = fmaf(c, zp.y, 0.5f * zown[4*q+1]);
                az[4*q+2] = fmaf(c, zp.z, 0.5f * zown[4*q+2]);
                az[4*q+3] = fmaf(c, zp.w, 0.5f * zown[4*q+3]);
            }
        } else {
            #pragma unroll
            for (int kk = 0; kk < 32; ++kk) az[kk] = zown[kk];
        }
    }
    __syncthreads();

    // ---- phase 1.5b: split hi/lo, write A-fragments (lane-major, conflict-free) ----
    {
        unsigned* fragH = (unsigned*)sAlias;
        unsigned* fragL = fragH + 4096;
        const int m = node >> 4;
        const int r = node & 15;
        #pragma unroll
        for (int g = 0; g < 4; ++g) {
            uint4 ph, pl;
            split2(az[8*g+0], az[8*g+1], ph.x, pl.x);
            split2(az[8*g+2], az[8*g+3], ph.y, pl.y);
            split2(az[8*g+4], az[8*g+5], ph.z, pl.z);
            split2(az[8*g+6], az[8*g+7], ph.w, pl.w);
            const int idx = ((m * 2 + s) * 64 + g * 16 + r) * 4;
            *(uint4*)&fragH[idx] = ph;
            *(uint4*)&fragL[idx] = pl;
        }
    }
    __syncthreads();

    // ---- phase 2: MFMA GEMM [128x64]x[64x128] split-bf16 3-pass + fused
    //      bias/relu/weighted-pool ----
    {
        const int w = tid >> 6;
        const int lane = tid & 63;
        const int r = lane & 15;
        const int g4 = lane >> 4;
        // B-fragments from ws (L2-resident), held in regs
        const uint4* wsB = (const uint4*)((const unsigned*)ws + WS_BF);
        uint4 Bh[2][2], Bl[2][2];
        #pragma unroll
        for (int ntl = 0; ntl < 2; ++ntl)
            #pragma unroll
            for (int ss = 0; ss < 2; ++ss) {
                const int n = 2 * w + ntl;
                Bh[ntl][ss] = wsB[((n * 2 + ss) * 2 + 0) * 64 + lane];
                Bl[ntl][ss] = wsB[((n * 2 + ss) * 2 + 1) * 64 + lane];
            }
        const float b2c0 = sb2[32 * w + r];
        const float b2c1 = sb2[32 * w + 16 + r];
        const unsigned* fragH = (const unsigned*)sAlias;
        const unsigned* fragL = fragH + 4096;

        for (int m = 0; m < 8; ++m) {
            s16x8 Ah[2], Al[2];
            #pragma unroll
            for (int ss = 0; ss < 2; ++ss) {
                Ah[ss] = *(const s16x8*)&fragH[((m * 2 + ss) * 64 + lane) * 4];
                Al[ss] = *(const s16x8*)&fragL[((m * 2 + ss) * 64 + lane) * 4];
            }
            f32x4 acc0 = {0.f, 0.f, 0.f, 0.f};
            f32x4 acc1 = {0.f, 0.f, 0.f, 0.f};
            #pragma unroll
            for (int ss = 0; ss < 2; ++ss) {
                const s16x8 bh0 = *(const s16x8*)&Bh[0][ss];
                const s16x8 bl0 = *(const s16x8*)&Bl[0][ss];
                const s16x8 bh1 = *(const s16x8*)&Bh[1][ss];
                const s16x8 bl1 = *(const s16x8*)&Bl[1][ss];
                acc0 = __builtin_amdgcn_mfma_f32_16x16x32_bf16(Ah[ss], bh0, acc0, 0, 0, 0);
                acc0 = __builtin_amdgcn_mfma_f32_16x16x32_bf16(Ah[ss], bl0, acc0, 0, 0, 0);
                acc0 = __builtin_amdgcn_mfma_f32_16x16x32_bf16(Al[ss], bh0, acc0, 0, 0, 0);
                acc1 = __builtin_amdgcn_mfma_f32_16x16x32_bf16(Ah[ss], bh1, acc1, 0, 0, 0);
                acc1 = __builtin_amdgcn_mfma_f32_16x16x32_bf16(Ah[ss], bl1, acc1, 0, 0, 0);
                acc1 = __builtin_amdgcn_mfma_f32_16x16x32_bf16(Al[ss], bh1, acc1, 0, 0, 0);
            }
            // epilogue: bias + relu + column-sum-weighted pool
            const int gA = (16 * m * 3121) >> 16;       // /21
            float pA0 = 0.f, pA1 = 0.f, pB0 = 0.f, pB1 = 0.f;
            #pragma unroll
            for (int i = 0; i < 4; ++i) {
                const int row = 16 * m + 4 * g4 + i;
                const int gg = (row * 3121) >> 16;
                const int j = row - 21 * gg;
                float wgt = (j == 0) ? (ROOT_COLSUM * (1.f / 21.f))
                          : (((j & 3) == 0) ? (0.5f / 21.f) : (1.f / 21.f));
                if (row >= Mrows) wgt = 0.f;
                const float z0 = fmaxf(acc0[i] + b2c0, 0.f);
                const float z1v = fmaxf(acc1[i] + b2c1, 0.f);
                if (gg == gA) { pA0 = fmaf(wgt, z0, pA0); pA1 = fmaf(wgt, z1v, pA1); }
                else          { pB0 = fmaf(wgt, z0, pB0); pB1 = fmaf(wgt, z1v, pB1); }
            }
            pA0 += __shfl_xor(pA0, 16); pA0 += __shfl_xor(pA0, 32);
            pA1 += __shfl_xor(pA1, 16); pA1 += __shfl_xor(pA1, 32);
            pB0 += __shfl_xor(pB0, 16); pB0 += __shfl_xor(pB0, 32);
            pB1 += __shfl_xor(pB1, 16); pB1 += __shfl_xor(pB1, 32);
            if (lane < 16) {
                const int gB = gA + 1;
                sP[gA * 128 + 32 * w + r]      += pA0;
                sP[gA * 128 + 32 * w + 16 + r] += pA1;
                if (gB < GPB) {
                    sP[gB * 128 + 32 * w + r]      += pB0;
                    sP[gB * 128 + 32 * w + 16 + r] += pB1;
                }
            }
        }
    }
    __syncthreads();

    // ---- stage W3T into alias buffer (frags dead) ----
    {
        float* sW3T = sAlias;                   // [29][132]
        for (int i = tid; i < 3712; i += 256)
            sW3T[(i >> 7) * 132 + (i & 127)] = ws[WS_W3T + i];
    }
    __syncthreads();

    // ---- phase 3: logits + log_softmax ----
    if (tid < nv * NCLS) {
        const int g = (tid * 2260) >> 16;       // /29 for tid<174
        const int c = tid - g * NCLS;
        const float* wrow = &sAlias[c * 132];
        const float* pg = &sP[g * 128];
        float acc3 = sb3[c];
        #pragma unroll
        for (int k = 0; k < 128; k += 4) {
            const float4 wv = *(const float4*)&wrow[k];
            const float4 pv = *(const float4*)&pg[k];
            acc3 = fmaf(pv.x, wv.x, acc3);
            acc3 = fmaf(pv.y, wv.y, acc3);
            acc3 = fmaf(pv.z, wv.z, acc3);
            acc3 = fmaf(pv.w, wv.w, acc3);
        }
        sLg[tid] = acc3;
    }
    __syncthreads();
    if (tid < nv) {
        float m = -1e30f;
        for (int c = 0; c < NCLS; ++c) m = fmaxf(m, sLg[tid * NCLS + c]);
        float sum = 0.f;
        for (int c = 0; c < NCLS; ++c) sum += expf(sLg[tid * NCLS + c] - m);
        sRed[tid * 2] = m;
        sRed[tid * 2 + 1] = logf(sum);
    }
    __syncthreads();
    if (tid < nv * NCLS) {
        const int g = (tid * 2260) >> 16;
        out[(long long)g0 * NCLS + tid] = sLg[tid] - sRed[g * 2] - sRed[g * 2 + 1];
    }
}

extern "C" void kernel_launch(void* const* d_in, const int* in_sizes, int n_in,
                              void* d_out, int out_size, void* d_ws, size_t ws_size,
                              hipStream_t stream) {
    const float* x   = (const float*)d_in[0];
    const float* W1  = (const float*)d_in[1];
    const float* b1  = (const float*)d_in[2];
    const float* g1  = (const float*)d_in[3];
    const float* be1 = (const float*)d_in[4];
    const float* m1  = (const float*)d_in[5];
    const float* v1  = (const float*)d_in[6];
    const float* W2  = (const float*)d_in[7];
    const float* b2  = (const float*)d_in[8];
    const float* g2  = (const float*)d_in[9];
    const float* be2 = (const float*)d_in[10];
    const float* m2  = (const float*)d_in[11];
    const float* v2  = (const float*)d_in[12];
    const float* W3  = (const float*)d_in[13];
    const float* b3  = (const float*)d_in[14];
    float* out = (float*)d_out;
    float* ws  = (float*)d_ws;

    prep_kernel<<<(WS_TOTAL + 255) / 256, 256, 0, stream>>>(
        W1, b1, g1, be1, m1, v1, W2, b2, g2, be2, m2, v2, W3, b3, ws);

    gcn_main<<<NCHUNK, 256, 0, stream>>>(x, ws, out);
}